// Round 4
// baseline (839.255 us; speedup 1.0000x reference)
//
#include <hip/hip_runtime.h>

#define NZ 32
#define NY 1024
#define NX 1024
#define TY 8   // y-rows marched per thread (grid: 4096 blocks -> 16/CU)

__device__ __forceinline__ float rcpf(float x) { return __builtin_amdgcn_rcpf(x); }

// Classic Jiang-Shu WENO5 reconstruction at the i+1/2 face (left-biased).
// Single-reciprocal formulation: a_k = c_k/e_k^2 rescaled by e0^2*e1^2*e2^2
// (identical weights; fp32-safe: e^2 in [1e-12, ~1e8]).
__device__ __forceinline__ float weno5(float qm2, float qm1, float q0, float qp1, float qp2) {
    const float c1312 = 13.0f / 12.0f;
    float t0 = qm2 - 2.0f * qm1 + q0;
    float u0 = qm2 - 4.0f * qm1 + 3.0f * q0;
    float b0 = c1312 * t0 * t0 + 0.25f * u0 * u0;
    float t1 = qm1 - 2.0f * q0 + qp1;
    float u1 = qm1 - qp1;
    float b1 = c1312 * t1 * t1 + 0.25f * u1 * u1;
    float t2 = q0 - 2.0f * qp1 + qp2;
    float u2 = 3.0f * q0 - 4.0f * qp1 + qp2;
    float b2 = c1312 * t2 * t2 + 0.25f * u2 * u2;
    float e0 = 1e-6f + b0, e1 = 1e-6f + b1, e2 = 1e-6f + b2;
    float s0 = e0 * e0, s1 = e1 * e1, s2 = e2 * e2;
    float a0 = 0.1f * (s1 * s2);
    float a1 = 0.6f * (s0 * s2);
    float a2 = 0.3f * (s0 * s1);
    float p0 = (1.0f / 3.0f) * qm2 + (-7.0f / 6.0f) * qm1 + (11.0f / 6.0f) * q0;
    float p1 = (-1.0f / 6.0f) * qm1 + (5.0f / 6.0f) * q0 + (1.0f / 3.0f) * qp1;
    float p2 = (1.0f / 3.0f) * q0 + (5.0f / 6.0f) * qp1 + (-1.0f / 6.0f) * qp2;
    // 1-ulp hardware reciprocal is far inside the tolerance.
    return (a0 * p0 + a1 * p1 + a2 * p2) * rcpf(a0 + a1 + a2);
}

// Upwinded flux at face i+1/2 given the 6-wide stencil q[i-2..i+3] and vel at cell i.
__device__ __forceinline__ float upwind_flux(float vel, float qm2, float qm1, float q0,
                                             float qp1, float qp2, float qp3) {
    bool up = vel >= 0.0f;
    float s0 = up ? qm2 : qp3;
    float s1 = up ? qm1 : qp2;
    float s2 = up ? q0  : qp1;
    float s3 = up ? qp1 : q0;
    float s4 = up ? qp2 : qm1;
    return vel * weno5(s0, s1, s2, s3, s4);
}

__global__ __launch_bounds__(256, 8) void adv_kernel(const float* __restrict__ h,
                                                     const float* __restrict__ u,
                                                     const float* __restrict__ v,
                                                     float* __restrict__ out) {
    const int tid = threadIdx.x;
    const int x0  = tid * 4;                 // this thread owns points x0..x0+3
    const int z   = blockIdx.z;
    const int y0  = blockIdx.y * TY;
    const size_t zoff = (size_t)z * (NY * NX);
    const float* __restrict__ hz = h + zoff;
    const float* __restrict__ uz = u + zoff;
    const float* __restrict__ vz = v + zoff;
    float* __restrict__ oz = out + zoff;

    if (z == 0 || z == NZ - 1) {
        // whole slab is exactly zero in the reference
#pragma unroll
        for (int t = 0; t < TY; ++t)
            *(float4*)(oz + (y0 + t) * NX + x0) = make_float4(0.f, 0.f, 0.f, 0.f);
        return;
    }

    // per-point x-interior masks (hoisted)
    const bool xin0 = (x0 + 0 >= 2) && (x0 + 0 <= NX - 3);
    const bool xin1 = (x0 + 1 >= 2) && (x0 + 1 <= NX - 3);
    const bool xin2 = (x0 + 2 >= 2) && (x0 + 2 <= NX - 3);
    const bool xin3 = (x0 + 3 >= 2) && (x0 + 3 <= NX - 3);
    const bool xfast = (x0 >= 4) && (x0 + 7 <= NX - 1);  // both halo float4s in-bounds
    const int  xm1   = x0 > 0 ? x0 - 1 : 0;

    // rolling y-window of own columns: hy[k] = h[z, clamp(y-3+k), x0..x0+3]
    float4 hy[7];
#pragma unroll
    for (int k = 0; k < 7; ++k) {
        int yy = y0 - 3 + k;
        yy = yy < 0 ? 0 : (yy > NY - 1 ? NY - 1 : yy);
        hy[k] = *(const float4*)(hz + yy * NX + x0);
    }

    // prologue: fluxes through face y0-1 for the 4 columns
    const int ym1 = (y0 > 0) ? y0 - 1 : 0;
    float4 vm = *(const float4*)(vz + ym1 * NX + x0);
    float4 fn_lo;
    fn_lo.x = upwind_flux(vm.x, hy[0].x, hy[1].x, hy[2].x, hy[3].x, hy[4].x, hy[5].x);
    fn_lo.y = upwind_flux(vm.y, hy[0].y, hy[1].y, hy[2].y, hy[3].y, hy[4].y, hy[5].y);
    fn_lo.z = upwind_flux(vm.z, hy[0].z, hy[1].z, hy[2].z, hy[3].z, hy[4].z, hy[5].z);
    fn_lo.w = upwind_flux(vm.w, hy[0].w, hy[1].w, hy[2].w, hy[3].w, hy[4].w, hy[5].w);

#pragma unroll 4
    for (int t = 0; t < TY; ++t) {
        const int y   = y0 + t;            // uniform across the block
        const int row = y * NX;
        const float* __restrict__ rp  = hz + row;
        const float* __restrict__ rpu = uz + row;

        // x-stencil s[0..10] = h[z, y, x0-4 .. x0+6] (edge-clamped);
        // middle 4 come free from the y-window.
        float s0, s1, s2, s3, s8, s9, s10;
        if (xfast) {
            float4 hm = *(const float4*)(rp + x0 - 4);
            float4 hp = *(const float4*)(rp + x0 + 4);
            s0 = hm.x; s1 = hm.y; s2 = hm.z; s3 = hm.w;
            s8 = hp.x; s9 = hp.y; s10 = hp.z;
        } else {
            // only waves containing tid 0 / 255 ever take this path
            int i0 = x0 - 4 < 0 ? 0 : x0 - 4;
            int i1 = x0 - 3 < 0 ? 0 : x0 - 3;
            int i2 = x0 - 2 < 0 ? 0 : x0 - 2;
            int i3 = x0 - 1 < 0 ? 0 : x0 - 1;
            int i8 = x0 + 4 > NX - 1 ? NX - 1 : x0 + 4;
            int i9 = x0 + 5 > NX - 1 ? NX - 1 : x0 + 5;
            int ia = x0 + 6 > NX - 1 ? NX - 1 : x0 + 6;
            s0 = rp[i0]; s1 = rp[i1]; s2 = rp[i2]; s3 = rp[i3];
            s8 = rp[i8]; s9 = rp[i9]; s10 = rp[ia];
        }
        const float s4 = hy[3].x, s5 = hy[3].y, s6 = hy[3].z, s7 = hy[3].w;

        float4 uu = *(const float4*)(rpu + x0);
        float  um = rpu[xm1];
        float4 vv = *(const float4*)(vz + row + x0);

        // x-face fluxes at faces x0-1 .. x0+3 (9 independent chains this iter)
        float fw = upwind_flux(um,   s1, s2, s3, s4, s5, s6);
        float f0 = upwind_flux(uu.x, s2, s3, s4, s5, s6, s7);
        float f1 = upwind_flux(uu.y, s3, s4, s5, s6, s7, s8);
        float f2 = upwind_flux(uu.z, s4, s5, s6, s7, s8, s9);
        float f3 = upwind_flux(uu.w, s5, s6, s7, s8, s9, s10);

        // y-face fluxes at face y for the 4 columns
        float fn0 = upwind_flux(vv.x, hy[1].x, hy[2].x, hy[3].x, hy[4].x, hy[5].x, hy[6].x);
        float fn1 = upwind_flux(vv.y, hy[1].y, hy[2].y, hy[3].y, hy[4].y, hy[5].y, hy[6].y);
        float fn2 = upwind_flux(vv.z, hy[1].z, hy[2].z, hy[3].z, hy[4].z, hy[5].z, hy[6].z);
        float fn3 = upwind_flux(vv.w, hy[1].w, hy[2].w, hy[3].w, hy[4].w, hy[5].w, hy[6].w);

        const float inv_d = 1.0f / 1000.0f;  // DX == DY
        const bool yin = (y >= 2) && (y <= NY - 3);
        float4 res;
        res.x = (xin0 && yin) ? -((f0 - fw) + (fn0 - fn_lo.x)) * inv_d : 0.0f;
        res.y = (xin1 && yin) ? -((f1 - f0) + (fn1 - fn_lo.y)) * inv_d : 0.0f;
        res.z = (xin2 && yin) ? -((f2 - f1) + (fn2 - fn_lo.z)) * inv_d : 0.0f;
        res.w = (xin3 && yin) ? -((f3 - f2) + (fn3 - fn_lo.w)) * inv_d : 0.0f;
        *(float4*)(oz + row + x0) = res;

        fn_lo = make_float4(fn0, fn1, fn2, fn3);
        // roll the window (static rotation)
#pragma unroll
        for (int k = 0; k < 6; ++k) hy[k] = hy[k + 1];
        int yn = y + 4;
        yn = yn > NY - 1 ? NY - 1 : yn;
        hy[6] = *(const float4*)(hz + yn * NX + x0);
    }
}

extern "C" void kernel_launch(void* const* d_in, const int* in_sizes, int n_in,
                              void* d_out, int out_size, void* d_ws, size_t ws_size,
                              hipStream_t stream) {
    const float* h = (const float*)d_in[0];
    const float* u = (const float*)d_in[1];
    const float* v = (const float*)d_in[2];
    float* out = (float*)d_out;

    dim3 block(256, 1, 1);
    dim3 grid(1, NY / TY, NZ);   // 4096 blocks; 4 points/thread in x
    adv_kernel<<<grid, block, 0, stream>>>(h, u, v, out);
}

// Round 5
// 388.205 us; speedup vs baseline: 2.1619x; 2.1619x over previous
//
#include <hip/hip_runtime.h>

#define NZ 32
#define NY 1024
#define NX 1024
#define TY 8     // y-rows marched per thread
#define BXT 128  // threads per block; each owns 4 x-points -> 512 columns/block

__device__ __forceinline__ float rcpf(float x) { return __builtin_amdgcn_rcpf(x); }

// Classic Jiang-Shu WENO5 reconstruction at the i+1/2 face (left-biased).
// Single-reciprocal formulation: a_k = c_k/e_k^2 rescaled by e0^2*e1^2*e2^2
// (identical weights; fp32-safe: e^2 in [1e-12, ~1e8]).
__device__ __forceinline__ float weno5(float qm2, float qm1, float q0, float qp1, float qp2) {
    const float c1312 = 13.0f / 12.0f;
    float t0 = qm2 - 2.0f * qm1 + q0;
    float u0 = qm2 - 4.0f * qm1 + 3.0f * q0;
    float b0 = c1312 * t0 * t0 + 0.25f * u0 * u0;
    float t1 = qm1 - 2.0f * q0 + qp1;
    float u1 = qm1 - qp1;
    float b1 = c1312 * t1 * t1 + 0.25f * u1 * u1;
    float t2 = q0 - 2.0f * qp1 + qp2;
    float u2 = 3.0f * q0 - 4.0f * qp1 + qp2;
    float b2 = c1312 * t2 * t2 + 0.25f * u2 * u2;
    float e0 = 1e-6f + b0, e1 = 1e-6f + b1, e2 = 1e-6f + b2;
    float s0 = e0 * e0, s1 = e1 * e1, s2 = e2 * e2;
    float a0 = 0.1f * (s1 * s2);
    float a1 = 0.6f * (s0 * s2);
    float a2 = 0.3f * (s0 * s1);
    float p0 = (1.0f / 3.0f) * qm2 + (-7.0f / 6.0f) * qm1 + (11.0f / 6.0f) * q0;
    float p1 = (-1.0f / 6.0f) * qm1 + (5.0f / 6.0f) * q0 + (1.0f / 3.0f) * qp1;
    float p2 = (1.0f / 3.0f) * q0 + (5.0f / 6.0f) * qp1 + (-1.0f / 6.0f) * qp2;
    // 1-ulp hardware reciprocal is far inside the tolerance.
    return (a0 * p0 + a1 * p1 + a2 * p2) * rcpf(a0 + a1 + a2);
}

// Upwinded flux at face i+1/2 given the 6-wide stencil q[i-2..i+3] and vel at cell i.
__device__ __forceinline__ float upwind_flux(float vel, float qm2, float qm1, float q0,
                                             float qp1, float qp2, float qp3) {
    bool up = vel >= 0.0f;
    float s0 = up ? qm2 : qp3;
    float s1 = up ? qm1 : qp2;
    float s2 = up ? q0  : qp1;
    float s3 = up ? qp1 : q0;
    float s4 = up ? qp2 : qm1;
    return vel * weno5(s0, s1, s2, s3, s4);
}

__global__ __launch_bounds__(128) void adv_kernel(const float* __restrict__ h,
                                                  const float* __restrict__ u,
                                                  const float* __restrict__ v,
                                                  float* __restrict__ out) {
    const int tid = threadIdx.x;
    const int x0  = blockIdx.x * (BXT * 4) + tid * 4;  // owns points x0..x0+3
    const int z   = blockIdx.z;
    const int y0  = blockIdx.y * TY;
    const size_t zoff = (size_t)z * (NY * NX);
    const float* __restrict__ hz = h + zoff;
    const float* __restrict__ uz = u + zoff;
    const float* __restrict__ vz = v + zoff;
    float* __restrict__ oz = out + zoff;

    if (z == 0 || z == NZ - 1) {
        // whole slab is exactly zero in the reference
#pragma unroll
        for (int t = 0; t < TY; ++t)
            *(float4*)(oz + (y0 + t) * NX + x0) = make_float4(0.f, 0.f, 0.f, 0.f);
        return;
    }

    // hoisted per-thread x facts
    const bool xin0 = (x0 + 0 >= 2) && (x0 + 0 <= NX - 3);
    const bool xin1 = (x0 + 1 >= 2) && (x0 + 1 <= NX - 3);
    const bool xin2 = (x0 + 2 >= 2) && (x0 + 2 <= NX - 3);
    const bool xin3 = (x0 + 3 >= 2) && (x0 + 3 <= NX - 3);
    const bool isL  = (x0 == 0);        // left-edge thread: x0-4..-1 clamp to 0
    const bool isR  = (x0 == NX - 4);   // right-edge thread: x0+4.. clamp to NX-1
    const int  ihm  = isL ? 0 : x0 - 4; // safe halo-load bases (values fixed below)
    const int  xm1  = isL ? 0 : x0 - 1;

    // rolling y-window of own columns: hy[k] = h[z, clamp(y-3+k), x0..x0+3]
    float4 hy[7];
#pragma unroll
    for (int k = 0; k < 7; ++k) {
        int yy = y0 - 3 + k;
        yy = yy < 0 ? 0 : (yy > NY - 1 ? NY - 1 : yy);
        hy[k] = *(const float4*)(hz + yy * NX + x0);
    }

    // prologue: fluxes through face y0-1 for the 4 columns
    const int ym1 = (y0 > 0) ? y0 - 1 : 0;
    float4 vm = *(const float4*)(vz + ym1 * NX + x0);
    float4 fn_lo;
    fn_lo.x = upwind_flux(vm.x, hy[0].x, hy[1].x, hy[2].x, hy[3].x, hy[4].x, hy[5].x);
    fn_lo.y = upwind_flux(vm.y, hy[0].y, hy[1].y, hy[2].y, hy[3].y, hy[4].y, hy[5].y);
    fn_lo.z = upwind_flux(vm.z, hy[0].z, hy[1].z, hy[2].z, hy[3].z, hy[4].z, hy[5].z);
    fn_lo.w = upwind_flux(vm.w, hy[0].w, hy[1].w, hy[2].w, hy[3].w, hy[4].w, hy[5].w);

#pragma unroll 4
    for (int t = 0; t < TY; ++t) {
        const int y   = y0 + t;            // uniform across the block
        const int row = y * NX;
        const float* __restrict__ rp  = hz + row;
        const float* __restrict__ rpu = uz + row;

        // ---- issue ALL loads up front (branchless; scheduler can pipeline) ----
        int yn = y + 4;
        yn = yn > NY - 1 ? NY - 1 : yn;
        float4 hy_next = *(const float4*)(hz + yn * NX + x0);  // window feed, row y+4
        // halo float4s: in-bounds addresses for every thread (isL uses base 0;
        // isR reads 4 floats past the row end, which is still inside the slab /
        // array — those lanes are repaired below). 16B-aligned in all cases.
        float4 hm = *(const float4*)(rp + ihm);
        float4 hp = *(const float4*)(rp + x0 + 4);
        float4 uu = *(const float4*)(rpu + x0);
        float  um = rpu[xm1];
        float4 vv = *(const float4*)(vz + row + x0);

        // x-stencil s0..s10 = h[z, y, x0-4 .. x0+6], edge-clamped.
        // middle 4 (s4..s7) come free from the y-window (= row y).
        const float s4 = hy[3].x, s5 = hy[3].y, s6 = hy[3].z, s7 = hy[3].w;
        // edge repair: clamped value equals the window-center edge element
        float s0 = isL ? s4 : hm.x;
        float s1 = isL ? s4 : hm.y;
        float s2 = isL ? s4 : hm.z;
        float s3 = isL ? s4 : hm.w;
        float s8  = isR ? s7 : hp.x;
        float s9  = isR ? s7 : hp.y;
        float s10 = isR ? s7 : hp.z;

        // x-face fluxes at faces x0-1 .. x0+3 (5 independent chains)
        float fw = upwind_flux(um,   s1, s2, s3, s4, s5, s6);
        float f0 = upwind_flux(uu.x, s2, s3, s4, s5, s6, s7);
        float f1 = upwind_flux(uu.y, s3, s4, s5, s6, s7, s8);
        float f2 = upwind_flux(uu.z, s4, s5, s6, s7, s8, s9);
        float f3 = upwind_flux(uu.w, s5, s6, s7, s8, s9, s10);

        // y-face fluxes at face y for the 4 columns (4 more chains)
        float fn0 = upwind_flux(vv.x, hy[1].x, hy[2].x, hy[3].x, hy[4].x, hy[5].x, hy[6].x);
        float fn1 = upwind_flux(vv.y, hy[1].y, hy[2].y, hy[3].y, hy[4].y, hy[5].y, hy[6].y);
        float fn2 = upwind_flux(vv.z, hy[1].z, hy[2].z, hy[3].z, hy[4].z, hy[5].z, hy[6].z);
        float fn3 = upwind_flux(vv.w, hy[1].w, hy[2].w, hy[3].w, hy[4].w, hy[5].w, hy[6].w);

        const float inv_d = 1.0f / 1000.0f;  // DX == DY
        const bool yin = (y >= 2) && (y <= NY - 3);
        float4 res;
        res.x = (xin0 && yin) ? -((f0 - fw) + (fn0 - fn_lo.x)) * inv_d : 0.0f;
        res.y = (xin1 && yin) ? -((f1 - f0) + (fn1 - fn_lo.y)) * inv_d : 0.0f;
        res.z = (xin2 && yin) ? -((f2 - f1) + (fn2 - fn_lo.z)) * inv_d : 0.0f;
        res.w = (xin3 && yin) ? -((f3 - f2) + (fn3 - fn_lo.w)) * inv_d : 0.0f;
        *(float4*)(oz + row + x0) = res;

        fn_lo = make_float4(fn0, fn1, fn2, fn3);
        // roll the window (static rotation inside the unroll-4 chunks)
#pragma unroll
        for (int k = 0; k < 6; ++k) hy[k] = hy[k + 1];
        hy[6] = hy_next;
    }
}

extern "C" void kernel_launch(void* const* d_in, const int* in_sizes, int n_in,
                              void* d_out, int out_size, void* d_ws, size_t ws_size,
                              hipStream_t stream) {
    const float* h = (const float*)d_in[0];
    const float* u = (const float*)d_in[1];
    const float* v = (const float*)d_in[2];
    float* out = (float*)d_out;

    dim3 block(BXT, 1, 1);
    dim3 grid(NX / (BXT * 4), NY / TY, NZ);  // 2 x 128 x 32 = 8192 two-wave blocks
    adv_kernel<<<grid, block, 0, stream>>>(h, u, v, out);
}